// Round 1
// baseline (148.630 us; speedup 1.0000x reference)
//
#include <hip/hip_runtime.h>

#define B_N 8
#define A_N 100000
#define M_N 64

__global__ __launch_bounds__(256) void rl_main(
    const float* __restrict__ regressions,   // (B, A, 2)
    const float* __restrict__ anchors,       // (1, A, 2)
    const float* __restrict__ annotations,   // (B, M, 3)
    float* __restrict__ ws_num, float* __restrict__ ws_cnt)
{
    __shared__ float4 ann[M_N];              // {x1, x2, len, valid}
    const int b = blockIdx.y;
    const int a = blockIdx.x * blockDim.x + threadIdx.x;

    if (threadIdx.x < M_N) {
        const float* p = annotations + (b * M_N + threadIdx.x) * 3;
        float x1 = p[0], x2 = p[1], lab = p[2];
        ann[threadIdx.x] = make_float4(x1, x2, x2 - x1, (lab != -1.0f) ? 1.0f : 0.0f);
    }
    __syncthreads();

    float local_sum = 0.0f, local_pos = 0.0f;
    if (a < A_N) {
        const float2 anc = ((const float2*)anchors)[a];
        const float a0 = anc.x, a1 = anc.y;
        const float aw = a1 - a0;
        const float acx = a0 + 0.5f * aw;

        // division-free max/argmax of iou = iw/ua (first-occurrence on ties)
        float iw_best = -1.0f, ua_best = 1.0f;   // encodes iou = -1
        int idx = 0;
        #pragma unroll 8
        for (int m = 0; m < M_N; ++m) {
            const float4 t = ann[m];
            if (t.w != 0.0f) {                   // valid annotation
                float iw = fminf(a1, t.y) - fmaxf(a0, t.x);
                iw = fmaxf(iw, 0.0f);
                const float ua = fmaxf(aw + t.z - iw, 1e-8f);
                if (iw * ua_best > iw_best * ua) { iw_best = iw; ua_best = ua; idx = m; }
            }
        }
        const float iou_max = iw_best / ua_best;
        if (iou_max >= 0.5f) {
            const float4 g = ann[idx];
            const float gw0 = g.y - g.x;
            const float gcx = g.x + 0.5f * gw0;
            const float gw  = fmaxf(gw0, 1.0f);
            const float tdx = ((gcx - acx) / aw) / 0.1f;
            const float tdw = logf(gw / aw) / 0.2f;
            const float2 rg = ((const float2*)regressions)[(size_t)b * A_N + a];
            const float d0 = fabsf(tdx - rg.x);
            const float d1 = fabsf(tdw - rg.y);
            const float inv9 = 1.0f / 9.0f;
            const float s0 = (d0 <= inv9) ? 4.5f * d0 * d0 : d0 - 0.5f / 9.0f;
            const float s1 = (d1 <= inv9) ? 4.5f * d1 * d1 : d1 - 0.5f / 9.0f;
            local_sum = s0 + s1;
            local_pos = 1.0f;
        }
    }

    // wave-64 reduce, then cross-wave via LDS, one atomic per block
    for (int o = 32; o > 0; o >>= 1) {
        local_sum += __shfl_down(local_sum, o, 64);
        local_pos += __shfl_down(local_pos, o, 64);
    }
    __shared__ float wsum[4], wpos[4];
    const int wid  = threadIdx.x >> 6;
    const int lane = threadIdx.x & 63;
    if (lane == 0) { wsum[wid] = local_sum; wpos[wid] = local_pos; }
    __syncthreads();
    if (threadIdx.x == 0) {
        const float s = wsum[0] + wsum[1] + wsum[2] + wsum[3];
        const float p = wpos[0] + wpos[1] + wpos[2] + wpos[3];
        atomicAdd(&ws_num[b], s);
        atomicAdd(&ws_cnt[b], p);
    }
}

__global__ void rl_final(const float* __restrict__ ws_num,
                         const float* __restrict__ ws_cnt,
                         float* __restrict__ out)
{
    if (blockIdx.x == 0 && threadIdx.x == 0) {
        float acc = 0.0f;
        for (int b = 0; b < B_N; ++b) {
            const float cnt = 2.0f * ws_cnt[b];
            const float num = ws_num[b];
            acc += (cnt > 0.0f) ? num / fmaxf(cnt, 1.0f) : 0.0f;
        }
        out[0] = acc / (float)B_N;
    }
}

extern "C" void kernel_launch(void* const* d_in, const int* in_sizes, int n_in,
                              void* d_out, int out_size, void* d_ws, size_t ws_size,
                              hipStream_t stream) {
    const float* regressions = (const float*)d_in[0];   // (8, 100000, 2)
    const float* anchors     = (const float*)d_in[1];   // (1, 100000, 2)
    const float* annotations = (const float*)d_in[2];   // (8, 64, 3)
    float* out = (float*)d_out;

    float* ws_num = (float*)d_ws;        // [B]
    float* ws_cnt = ws_num + B_N;        // [B]
    hipMemsetAsync(d_ws, 0, 2 * B_N * sizeof(float), stream);

    dim3 grid((A_N + 255) / 256, B_N);
    rl_main<<<grid, 256, 0, stream>>>(regressions, anchors, annotations, ws_num, ws_cnt);
    rl_final<<<1, 64, 0, stream>>>(ws_num, ws_cnt, out);
}

// Round 2
// 83.967 us; speedup vs baseline: 1.7701x; 1.7701x over previous
//
#include <hip/hip_runtime.h>

#define B_N 8
#define A_N 100000
#define M_N 64
#define ANCH 4
#define TPB 256
#define GX ((A_N + TPB * ANCH - 1) / (TPB * ANCH))   // 98 blocks per batch

__global__ __launch_bounds__(TPB) void rl_main(
    const float* __restrict__ regressions,   // (B, A, 2)
    const float* __restrict__ anchors,       // (1, A, 2)
    const float* __restrict__ annotations,   // (B, M, 3)
    float* __restrict__ ws_num, float* __restrict__ ws_cnt)
{
    __shared__ float4 ann[M_N];              // {x1, x2, len, unused}
    const int b = blockIdx.y;
    const int tid = threadIdx.x;

    if (tid < M_N) {
        const float* p = annotations + (b * M_N + tid) * 3;
        float x1 = p[0], x2 = p[1], lab = p[2];
        if (lab == -1.0f) { x1 = 1e30f; x2 = 1e30f; }
        // invalid => iw clamps to 0, len = 0, ua = aw > 0, iou = 0:
        // can only be argmax while best <= 0, and then iou_max = 0 < 0.5
        // so it never produces a positive. Branch-free inner loop.
        ann[tid] = make_float4(x1, x2, x2 - x1, 0.0f);
    }
    __syncthreads();

    const int abase = blockIdx.x * (TPB * ANCH) + tid;

    float a0[ANCH], a1[ANCH], aw[ANCH], iwb[ANCH], uab[ANCH];
    int idx[ANCH];
    bool act[ANCH];
    #pragma unroll
    for (int k = 0; k < ANCH; ++k) {
        const int a = abase + k * TPB;
        act[k] = (a < A_N);
        float2 anc = make_float2(0.0f, 1.0f);
        if (act[k]) anc = ((const float2*)anchors)[a];
        a0[k] = anc.x; a1[k] = anc.y; aw[k] = anc.y - anc.x;
        iwb[k] = -1.0f; uab[k] = 1.0f; idx[k] = 0;
    }

    // 4 independent division-free argmax chains; ann[m] broadcast shared x4
    #pragma unroll 8
    for (int m = 0; m < M_N; ++m) {
        const float4 t = ann[m];
        #pragma unroll
        for (int k = 0; k < ANCH; ++k) {
            float iw = fminf(a1[k], t.y) - fmaxf(a0[k], t.x);
            iw = fmaxf(iw, 0.0f);
            const float ua = (aw[k] + t.z) - iw;   // > 0 always (see staging)
            const bool better = iw * uab[k] > iwb[k] * ua;
            iwb[k] = better ? iw : iwb[k];
            uab[k] = better ? ua : uab[k];
            idx[k] = better ? m : idx[k];
        }
    }

    float lsum = 0.0f, lpos = 0.0f;
    #pragma unroll
    for (int k = 0; k < ANCH; ++k) {
        const float iou = iwb[k] / uab[k];        // exact gate, matches ref
        if (act[k] && iou >= 0.5f) {
            const float4 g = ann[idx[k]];
            const float gw0 = g.z;
            const float gcx = g.x + 0.5f * gw0;
            const float gw  = fmaxf(gw0, 1.0f);
            const float acx = a0[k] + 0.5f * aw[k];
            const float tdx = ((gcx - acx) / aw[k]) / 0.1f;
            const float tdw = logf(gw / aw[k]) / 0.2f;
            const float2 rg =
                ((const float2*)regressions)[(size_t)b * A_N + abase + k * TPB];
            const float d0 = fabsf(tdx - rg.x);
            const float d1 = fabsf(tdw - rg.y);
            const float inv9 = 1.0f / 9.0f;
            const float s0 = (d0 <= inv9) ? 4.5f * d0 * d0 : d0 - 0.5f / 9.0f;
            const float s1 = (d1 <= inv9) ? 4.5f * d1 * d1 : d1 - 0.5f / 9.0f;
            lsum += s0 + s1;
            lpos += 1.0f;
        }
    }

    // wave-64 reduce, cross-wave via LDS, one partial-slot write per block
    for (int o = 32; o > 0; o >>= 1) {
        lsum += __shfl_down(lsum, o, 64);
        lpos += __shfl_down(lpos, o, 64);
    }
    __shared__ float wsum[TPB / 64], wpos[TPB / 64];
    const int wid  = tid >> 6;
    const int lane = tid & 63;
    if (lane == 0) { wsum[wid] = lsum; wpos[wid] = lpos; }
    __syncthreads();
    if (tid == 0) {
        float s = 0.0f, p = 0.0f;
        #pragma unroll
        for (int w = 0; w < TPB / 64; ++w) { s += wsum[w]; p += wpos[w]; }
        const int slot = b * GX + blockIdx.x;
        ws_num[slot] = s;
        ws_cnt[slot] = p;
    }
}

__global__ __launch_bounds__(512) void rl_final(
    const float* __restrict__ ws_num,
    const float* __restrict__ ws_cnt,
    float* __restrict__ out)
{
    const int wid  = threadIdx.x >> 6;   // wave w handles batch w
    const int lane = threadIdx.x & 63;
    float s = 0.0f, c = 0.0f;
    for (int i = lane; i < GX; i += 64) {
        s += ws_num[wid * GX + i];
        c += ws_cnt[wid * GX + i];
    }
    for (int o = 32; o > 0; o >>= 1) {
        s += __shfl_down(s, o, 64);
        c += __shfl_down(c, o, 64);
    }
    __shared__ float pb[B_N];
    if (lane == 0) {
        const float cnt = 2.0f * c;
        pb[wid] = (cnt > 0.0f) ? s / fmaxf(cnt, 1.0f) : 0.0f;
    }
    __syncthreads();
    if (threadIdx.x == 0) {
        float acc = 0.0f;
        #pragma unroll
        for (int i = 0; i < B_N; ++i) acc += pb[i];
        out[0] = acc * (1.0f / (float)B_N);
    }
}

extern "C" void kernel_launch(void* const* d_in, const int* in_sizes, int n_in,
                              void* d_out, int out_size, void* d_ws, size_t ws_size,
                              hipStream_t stream) {
    const float* regressions = (const float*)d_in[0];
    const float* anchors     = (const float*)d_in[1];
    const float* annotations = (const float*)d_in[2];
    float* out = (float*)d_out;

    float* ws_num = (float*)d_ws;                 // [B_N * GX]
    float* ws_cnt = ws_num + B_N * GX;            // [B_N * GX]

    dim3 grid(GX, B_N);
    rl_main<<<grid, TPB, 0, stream>>>(regressions, anchors, annotations,
                                      ws_num, ws_cnt);
    rl_final<<<1, 512, 0, stream>>>(ws_num, ws_cnt, out);
}